// Round 14
// baseline (70.452 us; speedup 1.0000x reference)
//
#include <hip/hip_runtime.h>
#include <math.h>

#define BATCH 16
#define CHN   16
#define IMH   96
#define IMW   320
#define HW    (IMH*IMW)          /* 30720 */
#define PPB   128                /* points per block (2 lanes each -> 256 thr) */
#define NBLK  (HW/PPB)           /* 240 blocks per batch */
#define NPART 27                 /* 21 (sym H) + 6 (b) */
#define TWB   (HW*4)             /* tgt_w corner-record bytes per batch */
#define RECB  (HW*16)            /* fp4 y-pair record map bytes per batch */

typedef __attribute__((ext_vector_type(2))) float f32x2;

// 4-step DPP row reduce (row_shr 1/2/4/8): lane 15+16r holds the sum of its 16-lane row.
__device__ __forceinline__ float dpp_row_sum(float x) {
    union fi { float f; int i; };
    fi v; v.f = x;
#define DPPSTEP(CTRL) { fi t; t.i = __builtin_amdgcn_update_dpp(0, v.i, CTRL, 0xf, 0xf, true); v.f += t.f; }
    DPPSTEP(0x111)
    DPPSTEP(0x112)
    DPPSTEP(0x114)
    DPPSTEP(0x118)
#undef DPPSTEP
    return v.f;
}

// swap adjacent lanes (0<->1, 2<->3, ...): quad_perm [1,0,3,2] = 0xB1
__device__ __forceinline__ float dpp_swap_pair(float x) {
    union fi { float f; int i; };
    fi v; v.f = x;
    v.i = __builtin_amdgcn_update_dpp(0, v.i, 0xB1, 0xf, 0xf, true);
    return v.f;
}

// ---- kernel 0: quantize tgt_feat to fp4 y-pair records; tgt_w 4-corner dwords ----
// Record (x,y), 16B: [pix(x,y) 8B fp4x16ch | pix(x,min(y+1,95)) 8B].
__global__ __launch_bounds__(256) void build_maps(const float* __restrict__ in,
                                                  const float* __restrict__ tw,
                                                  char* __restrict__ rec,
                                                  char* __restrict__ twr) {
    const int b = blockIdx.y;
    const int p = blockIdx.x * 256 + threadIdx.x;
    const int y = p / IMW, x = p - y * IMW;
    const float* ip = in + (size_t)b * CHN * HW + p;
    float f[16];
#pragma unroll
    for (int c = 0; c < 16; ++c) f[c] = ip[c * HW];

    unsigned d0 = 0, d1 = 0;
    d0 = __builtin_amdgcn_cvt_scalef32_pk_fp4_f32(d0, f[0],  f[1],  1.0f, 0);
    d0 = __builtin_amdgcn_cvt_scalef32_pk_fp4_f32(d0, f[2],  f[3],  1.0f, 1);
    d0 = __builtin_amdgcn_cvt_scalef32_pk_fp4_f32(d0, f[4],  f[5],  1.0f, 2);
    d0 = __builtin_amdgcn_cvt_scalef32_pk_fp4_f32(d0, f[6],  f[7],  1.0f, 3);
    d1 = __builtin_amdgcn_cvt_scalef32_pk_fp4_f32(d1, f[8],  f[9],  1.0f, 0);
    d1 = __builtin_amdgcn_cvt_scalef32_pk_fp4_f32(d1, f[10], f[11], 1.0f, 1);
    d1 = __builtin_amdgcn_cvt_scalef32_pk_fp4_f32(d1, f[12], f[13], 1.0f, 2);
    d1 = __builtin_amdgcn_cvt_scalef32_pk_fp4_f32(d1, f[14], f[15], 1.0f, 3);
    int2 lv; lv.x = (int)d0; lv.y = (int)d1;
    char* rb = rec + (size_t)b * RECB;
    *(int2*)(rb + (size_t)p * 16) = lv;                               // own record lo
    if (y > 0)        *(int2*)(rb + (size_t)(p - IMW) * 16 + 8) = lv; // record above, hi
    if (y == IMH - 1) *(int2*)(rb + (size_t)p * 16 + 8) = lv;         // clamp row

    const float* twb = tw + (size_t)b * HW;
    const int xp1 = min(x + 1, IMW - 1), yp1 = min(y + 1, IMH - 1);
    const float v00 = twb[p];
    const float v01 = twb[y * IMW + xp1];
    const float v10 = twb[yp1 * IMW + x];
    const float v11 = twb[yp1 * IMW + xp1];
    int wq = __builtin_amdgcn_cvt_pk_fp8_f32(v00, v01, 0, false);
    wq     = __builtin_amdgcn_cvt_pk_fp8_f32(v10, v11, wq, true);
    ((int*)(twr + (size_t)b * TWB))[p] = wq;
}

// ---- kernel 1: 2 lanes per point (sample-split), per-block partial H/b ----
__global__ __launch_bounds__(256, 6) void gn_accum(
    const float* __restrict__ p2,
    const float* __restrict__ P2,
    const float* __restrict__ calibK,
    const float* __restrict__ weight,
    const float* __restrict__ src_feat,
    const float* __restrict__ src_w,
    const char* __restrict__ twr,
    const char* __restrict__ rec,
    float* __restrict__ partials)        // (B, NBLK, NPART)
{
    __shared__ float xs_l[640];
    __shared__ float ys_l[640];
    __shared__ float red[16][NPART];

    // XCD pinning: XCD k serves batches {k, k+8}
    const int n   = blockIdx.x;
    const int b   = n & 15;
    const int blk = n >> 4;              // 0..239
    const int t   = threadIdx.x;
    const int m   = t >> 1;              // point within block (0..127)
    const int h   = t & 1;               // lane role: 0 = samples 0,1,2; 1 = samples 3,4
    const int pp  = blk * PPB + m;

    // ---- cooperative coalesced stage of the block's 640 grid coords ----
    const unsigned Gblk0 = ((unsigned)b * HW + (unsigned)(blk * PPB)) * 5u;
#pragma unroll
    for (int j = 0; j < 3; ++j) {
        const unsigned idx = (unsigned)(j * 256 + t);
        if (idx < 640) {
            const unsigned G    = Gblk0 + idx;
            const unsigned sBig = G / (unsigned)(BATCH * HW);
            const unsigned r    = G - sBig * (unsigned)(BATCH * HW);
            const unsigned bb   = r / (unsigned)HW;
            const unsigned q    = r - bb * (unsigned)HW;
            const float* pb = p2 + (size_t)bb * (10 * HW) + (size_t)sBig * HW + q;
            xs_l[idx] = pb[0];
            ys_l[idx] = pb[5 * HW];
        }
    }
    __syncthreads();

    // ---- per-lane sample geometry: A slots = s0,s1,s2; B slots = s3,s4,s0 ----
    float wx0s = 0.f, wy0s = 0.f;
    int   twoff = 0;
    int   o[3];
    float W[3][4];
#pragma unroll
    for (int ls = 0; ls < 3; ++ls) {
        const int s = h ? ((ls == 0) ? 3 : (ls == 1) ? 4 : 0) : ls;
        const float xp = xs_l[5 * m + s];
        const float yp = ys_l[5 * m + s];
        float gx = 2.0f * (xp + 0.5f) / (float)IMW - 1.0f;
        float gy = 2.0f * (yp + 0.5f) / (float)IMH - 1.0f;
        float x  = (gx + 1.0f) * ((float)IMW * 0.5f) - 0.5f;
        float y  = (gy + 1.0f) * ((float)IMH * 0.5f) - 0.5f;
        float x0 = floorf(x), y0 = floorf(y);
        float wx = x - x0, wy = y - y0;
        int xi = (int)x0, yi = (int)y0;
        xi = min(max(xi, 0), IMW - 2);
        yi = min(max(yi, 0), IMH - 2);
        o[ls] = (yi * IMW + xi) * 16;
        W[ls][0] = (1.0f - wx) * (1.0f - wy);
        W[ls][1] = wx * (1.0f - wy);
        W[ls][2] = (1.0f - wx) * wy;
        W[ls][3] = wx * wy;
        if (s == 0) { twoff = (yi * IMW + xi) * 4; wx0s = wx; wy0s = wy; }
    }

    // ---- scattered gathers: A issues 6, B issues 4 (exec-masked; no dups) ----
    const char* mapb = rec + (size_t)b * RECB;
    int4 g0 = *(const int4*)(mapb + o[0]);
    int4 g1 = *(const int4*)(mapb + o[0] + 16);
    int4 g2 = *(const int4*)(mapb + o[1]);
    int4 g3 = *(const int4*)(mapb + o[1] + 16);
    int4 g4 = g0, g5 = g1;
    if (h == 0) {
        g4 = *(const int4*)(mapb + o[2]);
        g5 = *(const int4*)(mapb + o[2] + 16);
    }
    // same-address within pair -> merged requests:
    const int twq = *(const int*)(twr + (size_t)b * TWB + twoff);
    float srcv[16];
    const float* srcb = src_feat + (size_t)b * CHN * HW + pp;
#pragma unroll
    for (int c = 0; c < 16; ++c) srcv[c] = srcb[c * HW];
    const float* P2b = P2 + (size_t)b * 3 * HW;
    const float X = P2b[pp], Y = P2b[HW + pp], Z = P2b[2 * HW + pp];
    const float wP  = weight[(size_t)b * HW + pp];
    const float swP = src_w[(size_t)b * HW + pp];

    // ---- w (both lanes; all inputs pair-uniform) ----
    float wtw;
    {
        f32x2 wlo = __builtin_amdgcn_cvt_pk_f32_fp8(twq, false);
        f32x2 whi = __builtin_amdgcn_cvt_pk_f32_fp8(twq, true);
        wtw = wlo[0] * (1.0f - wx0s) * (1.0f - wy0s) + wlo[1] * wx0s * (1.0f - wy0s)
            + whi[0] * (1.0f - wx0s) * wy0s          + whi[1] * wx0s * wy0s;
    }
    const float w = swP * wtw * wP;

    // ---- decode fp4 + bilinear mix + moments (A accumulates; B supplies gy) ----
    f32x2 SxxV = {0.f,0.f}, SxyV = {0.f,0.f}, SyyV = {0.f,0.f}, TxV = {0.f,0.f}, TyV = {0.f,0.f};
#define MIX(GA, GB, WQ, H, K) ( \
      __builtin_amdgcn_cvt_scalef32_pk_f32_fp4((H) ? GA.y : GA.x, 1.0f, K) * WQ[0] \
    + __builtin_amdgcn_cvt_scalef32_pk_f32_fp4((H) ? GB.y : GB.x, 1.0f, K) * WQ[1] \
    + __builtin_amdgcn_cvt_scalef32_pk_f32_fp4((H) ? GA.w : GA.z, 1.0f, K) * WQ[2] \
    + __builtin_amdgcn_cvt_scalef32_pk_f32_fp4((H) ? GB.w : GB.z, 1.0f, K) * WQ[3] )
#define PAIRSTEP(H, K) {                                                          \
        f32x2 a0 = MIX(g0, g1, W[0], H, K);                                       \
        f32x2 a1 = MIX(g2, g3, W[1], H, K);                                       \
        f32x2 a2 = MIX(g4, g5, W[2], H, K);                                       \
        f32x2 snd = (a0 - a1) * 0.5f;   /* on B: gy = (f3-f4)/2 */                \
        f32x2 gyv;                                                                \
        gyv[0] = dpp_swap_pair(snd[0]);                                           \
        gyv[1] = dpp_swap_pair(snd[1]);                                           \
        const f32x2 sr = { srcv[(H) * 8 + 2 * (K)], srcv[(H) * 8 + 2 * (K) + 1] };\
        f32x2 resv = sr - a0;           /* on A: src - f0 */                      \
        f32x2 gxv  = (a1 - a2) * 0.5f;  /* on A: (f1-f2)/2 */                     \
        SxxV += gxv * gxv; SxyV += gxv * gyv; SyyV += gyv * gyv;                  \
        TxV  += resv * gxv; TyV += resv * gyv; }
    PAIRSTEP(0, 0) PAIRSTEP(0, 1) PAIRSTEP(0, 2) PAIRSTEP(0, 3)
    PAIRSTEP(1, 0) PAIRSTEP(1, 1) PAIRSTEP(1, 2) PAIRSTEP(1, 3)
#undef PAIRSTEP
#undef MIX

    // B lanes carry garbage accumulators -> mask to zero (bitwise select kills nan)
    const float Sxx = h ? 0.0f : (SxxV[0] + SxxV[1]);
    const float Sxy = h ? 0.0f : (SxyV[0] + SxyV[1]);
    const float Syy = h ? 0.0f : (SyyV[0] + SyyV[1]);
    const float Tx  = h ? 0.0f : (TxV[0]  + TxV[1]);
    const float Ty  = h ? 0.0f : (TyV[0]  + TyV[1]);

    // ---- Jacobian rows (after loop; X,Y,Z pair-uniform and valid on both lanes) ----
    const float fx = calibK[b * 9 + 0];
    const float fy = calibK[b * 9 + 4];
    const float fxZ = fx / Z, fyZ = fy / Z;
    const float fxXZ2 = fxZ * X / Z;
    const float fyYZ2 = fyZ * Y / Z;
    float r0[6] = { fxZ, 0.0f, -fxXZ2, -fxXZ2 * Y, fx + fxXZ2 * X, -fxZ * Y };
    float r1[6] = { 0.0f, fyZ, -fyYZ2, -fy - fyYZ2 * Y, fyYZ2 * X, fyZ * X };

    const float Pm = w * Sxx, Qm = w * Sxy, Rm = w * Syy;
    const float tx = w * Tx,  ty = w * Ty;

    // ---- rank-2 H: H(k,l) = r0[k]*a[l] + r1[k]*c[l]  (B lanes: all zero) ----
    float av[6], cv[6];
#pragma unroll
    for (int k = 0; k < 6; ++k) {
        av[k] = Pm * r0[k] + Qm * r1[k];
        cv[k] = Qm * r0[k] + Rm * r1[k];
    }

    // ---- 27 values: 4-step DPP row sum -> 16 LDS rows -> block combine ----
    const int wv   = t >> 6;
    const int lane = t & 63;
    const int rrow = (wv << 2) | (lane >> 4);
    const bool wr  = (lane & 15) == 15;

    int idx = 0;
#pragma unroll
    for (int k = 0; k < 6; ++k) {
#pragma unroll
        for (int l = 0; l < 6; ++l) {
            if (l < k) continue;
            float v = r0[k] * av[l] + r1[k] * cv[l];
            v = dpp_row_sum(v);
            if (wr) red[rrow][idx] = v;
            ++idx;
        }
    }
#pragma unroll
    for (int k = 0; k < 6; ++k) {
        float v = tx * r0[k] + ty * r1[k];
        v = dpp_row_sum(v);
        if (wr) red[rrow][21 + k] = v;
    }
    __syncthreads();
    if (t < NPART) {
        float s = 0.0f;
#pragma unroll
        for (int r = 0; r < 16; ++r) s += red[r][t];
        partials[((size_t)b * NBLK + blk) * NPART + t] = s;
    }
}

// ---------------- kernel 2: double reduce + solve + se3_exp + compose ----------------
__global__ __launch_bounds__(256) void gn_solve(
    const float* __restrict__ partials,
    const float* __restrict__ poses,
    float* __restrict__ out)
{
    const int b = blockIdx.x;
    const int t = threadIdx.x;
    __shared__ double dsum[8][NPART];
    __shared__ double sums[NPART];

    if (t < 216) {
        const int col = t % NPART;
        const int g   = t / NPART;
        double s = 0.0;
        for (int j = g; j < NBLK; j += 8)
            s += (double)partials[((size_t)b * NBLK + j) * NPART + col];
        dsum[g][col] = s;
    }
    __syncthreads();
    if (t < NPART) {
        double s = 0.0;
#pragma unroll
        for (int g = 0; g < 8; ++g) s += dsum[g][t];
        sums[t] = s;
    }
    __syncthreads();
    if (t != 0) return;

    double A[6][7];
    {
        int idx = 0;
        for (int k = 0; k < 6; ++k)
            for (int l = k; l < 6; ++l) {
                A[k][l] = sums[idx];
                A[l][k] = sums[idx];
                ++idx;
            }
        for (int k = 0; k < 6; ++k) A[k][6] = sums[21 + k];
    }
    for (int col = 0; col < 6; ++col) {
        int piv = col; double mx = fabs(A[col][col]);
        for (int rr = col + 1; rr < 6; ++rr) {
            double v = fabs(A[rr][col]);
            if (v > mx) { mx = v; piv = rr; }
        }
        if (piv != col)
            for (int j = col; j < 7; ++j) { double tmp = A[col][j]; A[col][j] = A[piv][j]; A[piv][j] = tmp; }
        double d = A[col][col];
        for (int rr = col + 1; rr < 6; ++rr) {
            double f = A[rr][col] / d;
            for (int j = col; j < 7; ++j) A[rr][j] -= f * A[col][j];
        }
    }
    double x[6];
    for (int i = 5; i >= 0; --i) {
        double s = A[i][6];
        for (int j = i + 1; j < 6; ++j) s -= A[i][j] * x[j];
        x[i] = s / A[i][i];
    }

    const double rho[3] = { x[0], x[1], x[2] };
    const double phi[3] = { x[3], x[4], x[5] };
    const double th2 = phi[0]*phi[0] + phi[1]*phi[1] + phi[2]*phi[2];
    const bool small = th2 < 1e-8;
    const double th2s = small ? 1.0 : th2;
    const double th = sqrt(th2s);
    const double Ac = small ? 1.0 - th2 / 6.0   : sin(th) / th;
    const double Bc = small ? 0.5 - th2 / 24.0  : (1.0 - cos(th)) / th2s;
    const double Cc = small ? 1.0/6.0 - th2/120.0 : (th - sin(th)) / (th2s * th);
    const double Kh[3][3] = { { 0.0, -phi[2],  phi[1] },
                              {  phi[2], 0.0, -phi[0] },
                              { -phi[1],  phi[0], 0.0 } };
    double K2[3][3];
    for (int i = 0; i < 3; ++i)
        for (int j = 0; j < 3; ++j) {
            double s = 0.0;
            for (int k = 0; k < 3; ++k) s += Kh[i][k] * Kh[k][j];
            K2[i][j] = s;
        }
    double T[4][4];
    for (int i = 0; i < 3; ++i)
        for (int j = 0; j < 3; ++j) {
            double I = (i == j) ? 1.0 : 0.0;
            T[i][j] = I + Ac * Kh[i][j] + Bc * K2[i][j];
        }
    for (int i = 0; i < 3; ++i) {
        double s = 0.0;
        for (int j = 0; j < 3; ++j) {
            double I = (i == j) ? 1.0 : 0.0;
            double V = I + Bc * Kh[i][j] + Cc * K2[i][j];
            s += V * rho[j];
        }
        T[i][3] = s;
    }
    T[3][0] = 0.0; T[3][1] = 0.0; T[3][2] = 0.0; T[3][3] = 1.0;

    const float* pz = poses + b * 16;
    for (int i = 0; i < 4; ++i)
        for (int j = 0; j < 4; ++j) {
            double s = 0.0;
            for (int k = 0; k < 4; ++k) s += T[i][k] * (double)pz[k * 4 + j];
            out[b * 16 + i * 4 + j] = (float)s;
        }
    for (int k = 0; k < 6; ++k)
        out[BATCH * 16 + b * 6 + k] = (float)x[k];
}

extern "C" void kernel_launch(void* const* d_in, const int* in_sizes, int n_in,
                              void* d_out, int out_size, void* d_ws, size_t ws_size,
                              hipStream_t stream) {
    const float* poses    = (const float*)d_in[0];
    const float* calibK   = (const float*)d_in[1];
    const float* p2       = (const float*)d_in[2];
    const float* P2       = (const float*)d_in[3];
    const float* weight   = (const float*)d_in[4];
    const float* src_feat = (const float*)d_in[5];
    const float* tgt_feat = (const float*)d_in[6];
    const float* src_w    = (const float*)d_in[7];
    const float* tgt_w    = (const float*)d_in[8];
    float* out = (float*)d_out;

    char*  rec      = (char*)d_ws;                               // 16*RECB = 7.9 MB
    char*  twr      = rec + (size_t)BATCH * RECB;                // 16*TWB  = 2.0 MB
    float* partials = (float*)(twr + (size_t)BATCH * TWB);       // 0.66 MB (total 10.5 MB)

    hipLaunchKernelGGL(build_maps, dim3(HW / 256, BATCH), dim3(256), 0, stream,
                       tgt_feat, tgt_w, rec, twr);
    hipLaunchKernelGGL(gn_accum, dim3(NBLK * BATCH), dim3(256), 0, stream,
                       p2, P2, calibK, weight, src_feat, src_w, twr, rec, partials);
    hipLaunchKernelGGL(gn_solve, dim3(BATCH), dim3(256), 0, stream,
                       partials, poses, out);
}

// Round 15
// 58.140 us; speedup vs baseline: 1.2118x; 1.2118x over previous
//
#include <hip/hip_runtime.h>
#include <math.h>

#define BATCH 16
#define CHN   16
#define IMH   96
#define IMW   320
#define HW    (IMH*IMW)          /* 30720 */
#define PPB   128                /* points per block (2 lanes each -> 256 thr) */
#define NBLK  (HW/PPB)           /* 240 blocks per batch */
#define NPART 27                 /* 21 (sym H) + 6 (b) */
#define TWB   (HW*4)             /* tgt_w corner-record bytes per batch */
#define RECB  (HW*16)            /* fp4 y-pair record map bytes per batch */

typedef __attribute__((ext_vector_type(2))) float f32x2;

// 4-step DPP row reduce (row_shr 1/2/4/8): lane 15+16r holds the sum of its 16-lane row.
__device__ __forceinline__ float dpp_row_sum(float x) {
    union fi { float f; int i; };
    fi v; v.f = x;
#define DPPSTEP(CTRL) { fi t; t.i = __builtin_amdgcn_update_dpp(0, v.i, CTRL, 0xf, 0xf, true); v.f += t.f; }
    DPPSTEP(0x111)
    DPPSTEP(0x112)
    DPPSTEP(0x114)
    DPPSTEP(0x118)
#undef DPPSTEP
    return v.f;
}

// swap adjacent lanes (0<->1, 2<->3, ...): quad_perm [1,0,3,2] = 0xB1
__device__ __forceinline__ float dpp_swap_pair(float x) {
    union fi { float f; int i; };
    fi v; v.f = x;
    v.i = __builtin_amdgcn_update_dpp(0, v.i, 0xB1, 0xf, 0xf, true);
    return v.f;
}

// ---- kernel 0: quantize tgt_feat to fp4 y-pair records; tgt_w 4-corner dwords ----
// Record (x,y), 16B: [pix(x,y) 8B fp4x16ch | pix(x,min(y+1,95)) 8B].
__global__ __launch_bounds__(256) void build_maps(const float* __restrict__ in,
                                                  const float* __restrict__ tw,
                                                  char* __restrict__ rec,
                                                  char* __restrict__ twr) {
    const int b = blockIdx.y;
    const int p = blockIdx.x * 256 + threadIdx.x;
    const int y = p / IMW, x = p - y * IMW;
    const float* ip = in + (size_t)b * CHN * HW + p;
    float f[16];
#pragma unroll
    for (int c = 0; c < 16; ++c) f[c] = ip[c * HW];

    unsigned d0 = 0, d1 = 0;
    d0 = __builtin_amdgcn_cvt_scalef32_pk_fp4_f32(d0, f[0],  f[1],  1.0f, 0);
    d0 = __builtin_amdgcn_cvt_scalef32_pk_fp4_f32(d0, f[2],  f[3],  1.0f, 1);
    d0 = __builtin_amdgcn_cvt_scalef32_pk_fp4_f32(d0, f[4],  f[5],  1.0f, 2);
    d0 = __builtin_amdgcn_cvt_scalef32_pk_fp4_f32(d0, f[6],  f[7],  1.0f, 3);
    d1 = __builtin_amdgcn_cvt_scalef32_pk_fp4_f32(d1, f[8],  f[9],  1.0f, 0);
    d1 = __builtin_amdgcn_cvt_scalef32_pk_fp4_f32(d1, f[10], f[11], 1.0f, 1);
    d1 = __builtin_amdgcn_cvt_scalef32_pk_fp4_f32(d1, f[12], f[13], 1.0f, 2);
    d1 = __builtin_amdgcn_cvt_scalef32_pk_fp4_f32(d1, f[14], f[15], 1.0f, 3);
    int2 lv; lv.x = (int)d0; lv.y = (int)d1;
    char* rb = rec + (size_t)b * RECB;
    *(int2*)(rb + (size_t)p * 16) = lv;                               // own record lo
    if (y > 0)        *(int2*)(rb + (size_t)(p - IMW) * 16 + 8) = lv; // record above, hi
    if (y == IMH - 1) *(int2*)(rb + (size_t)p * 16 + 8) = lv;         // clamp row

    const float* twb = tw + (size_t)b * HW;
    const int xp1 = min(x + 1, IMW - 1), yp1 = min(y + 1, IMH - 1);
    const float v00 = twb[p];
    const float v01 = twb[y * IMW + xp1];
    const float v10 = twb[yp1 * IMW + x];
    const float v11 = twb[yp1 * IMW + xp1];
    int wq = __builtin_amdgcn_cvt_pk_fp8_f32(v00, v01, 0, false);
    wq     = __builtin_amdgcn_cvt_pk_fp8_f32(v10, v11, wq, true);
    ((int*)(twr + (size_t)b * TWB))[p] = wq;
}

// ---- kernel 1: 2 lanes per point (sample-split), per-block partial H/b ----
// __launch_bounds__(256,4): 128-VGPR cap -> no spill (R13's (256,6)=40 VGPR spilled).
__global__ __launch_bounds__(256, 4) void gn_accum(
    const float* __restrict__ p2,
    const float* __restrict__ P2,
    const float* __restrict__ calibK,
    const float* __restrict__ weight,
    const float* __restrict__ src_feat,
    const float* __restrict__ src_w,
    const char* __restrict__ twr,
    const char* __restrict__ rec,
    float* __restrict__ partials)        // (B, NBLK, NPART)
{
    __shared__ float xs_l[640];
    __shared__ float ys_l[640];
    __shared__ float red[16][NPART];

    // XCD pinning: XCD k serves batches {k, k+8}
    const int n   = blockIdx.x;
    const int b   = n & 15;
    const int blk = n >> 4;              // 0..239
    const int t   = threadIdx.x;
    const int m   = t >> 1;              // point within block (0..127)
    const int h   = t & 1;               // lane role: 0 = samples 0,1,2; 1 = samples 3,4
    const int pp  = blk * PPB + m;

    // ---- cooperative coalesced stage of the block's 640 grid coords ----
    const unsigned Gblk0 = ((unsigned)b * HW + (unsigned)(blk * PPB)) * 5u;
#pragma unroll
    for (int j = 0; j < 3; ++j) {
        const unsigned idx = (unsigned)(j * 256 + t);
        if (idx < 640) {
            const unsigned G    = Gblk0 + idx;
            const unsigned sBig = G / (unsigned)(BATCH * HW);
            const unsigned r    = G - sBig * (unsigned)(BATCH * HW);
            const unsigned bb   = r / (unsigned)HW;
            const unsigned q    = r - bb * (unsigned)HW;
            const float* pb = p2 + (size_t)bb * (10 * HW) + (size_t)sBig * HW + q;
            xs_l[idx] = pb[0];
            ys_l[idx] = pb[5 * HW];
        }
    }
    __syncthreads();

    // ---- per-lane sample geometry: A slots = s0,s1,s2; B slots = s3,s4,s0 ----
    float wx0s = 0.f, wy0s = 0.f;
    int   twoff = 0;
    int   o[3];
    float W[3][4];
#pragma unroll
    for (int ls = 0; ls < 3; ++ls) {
        const int s = h ? ((ls == 0) ? 3 : (ls == 1) ? 4 : 0) : ls;
        const float xp = xs_l[5 * m + s];
        const float yp = ys_l[5 * m + s];
        float gx = 2.0f * (xp + 0.5f) / (float)IMW - 1.0f;
        float gy = 2.0f * (yp + 0.5f) / (float)IMH - 1.0f;
        float x  = (gx + 1.0f) * ((float)IMW * 0.5f) - 0.5f;
        float y  = (gy + 1.0f) * ((float)IMH * 0.5f) - 0.5f;
        float x0 = floorf(x), y0 = floorf(y);
        float wx = x - x0, wy = y - y0;
        int xi = (int)x0, yi = (int)y0;
        xi = min(max(xi, 0), IMW - 2);
        yi = min(max(yi, 0), IMH - 2);
        o[ls] = (yi * IMW + xi) * 16;
        W[ls][0] = (1.0f - wx) * (1.0f - wy);
        W[ls][1] = wx * (1.0f - wy);
        W[ls][2] = (1.0f - wx) * wy;
        W[ls][3] = wx * wy;
        if (s == 0) { twoff = (yi * IMW + xi) * 4; wx0s = wx; wy0s = wy; }
    }

    // ---- scattered gathers: A issues 6, B issues 4 (exec-masked; no dups) ----
    const char* mapb = rec + (size_t)b * RECB;
    int4 g0 = *(const int4*)(mapb + o[0]);
    int4 g1 = *(const int4*)(mapb + o[0] + 16);
    int4 g2 = *(const int4*)(mapb + o[1]);
    int4 g3 = *(const int4*)(mapb + o[1] + 16);
    int4 g4 = g0, g5 = g1;
    if (h == 0) {
        g4 = *(const int4*)(mapb + o[2]);
        g5 = *(const int4*)(mapb + o[2] + 16);
    }
    // same-address within pair -> merged requests:
    const int twq = *(const int*)(twr + (size_t)b * TWB + twoff);
    float srcv[16];
    const float* srcb = src_feat + (size_t)b * CHN * HW + pp;
#pragma unroll
    for (int c = 0; c < 16; ++c) srcv[c] = srcb[c * HW];
    const float* P2b = P2 + (size_t)b * 3 * HW;
    const float X = P2b[pp], Y = P2b[HW + pp], Z = P2b[2 * HW + pp];
    const float wP  = weight[(size_t)b * HW + pp];
    const float swP = src_w[(size_t)b * HW + pp];

    // ---- w (both lanes; all inputs pair-uniform) ----
    float wtw;
    {
        f32x2 wlo = __builtin_amdgcn_cvt_pk_f32_fp8(twq, false);
        f32x2 whi = __builtin_amdgcn_cvt_pk_f32_fp8(twq, true);
        wtw = wlo[0] * (1.0f - wx0s) * (1.0f - wy0s) + wlo[1] * wx0s * (1.0f - wy0s)
            + whi[0] * (1.0f - wx0s) * wy0s          + whi[1] * wx0s * wy0s;
    }
    const float w = swP * wtw * wP;

    // ---- decode fp4 + bilinear mix + moments (A accumulates; B supplies gy) ----
    f32x2 SxxV = {0.f,0.f}, SxyV = {0.f,0.f}, SyyV = {0.f,0.f}, TxV = {0.f,0.f}, TyV = {0.f,0.f};
#define MIX(GA, GB, WQ, H, K) ( \
      __builtin_amdgcn_cvt_scalef32_pk_f32_fp4((H) ? GA.y : GA.x, 1.0f, K) * WQ[0] \
    + __builtin_amdgcn_cvt_scalef32_pk_f32_fp4((H) ? GB.y : GB.x, 1.0f, K) * WQ[1] \
    + __builtin_amdgcn_cvt_scalef32_pk_f32_fp4((H) ? GA.w : GA.z, 1.0f, K) * WQ[2] \
    + __builtin_amdgcn_cvt_scalef32_pk_f32_fp4((H) ? GB.w : GB.z, 1.0f, K) * WQ[3] )
#define PAIRSTEP(H, K) {                                                          \
        f32x2 a0 = MIX(g0, g1, W[0], H, K);                                       \
        f32x2 a1 = MIX(g2, g3, W[1], H, K);                                       \
        f32x2 a2 = MIX(g4, g5, W[2], H, K);                                       \
        f32x2 snd = (a0 - a1) * 0.5f;   /* on B: gy = (f3-f4)/2 */                \
        f32x2 gyv;                                                                \
        gyv[0] = dpp_swap_pair(snd[0]);                                           \
        gyv[1] = dpp_swap_pair(snd[1]);                                           \
        const f32x2 sr = { srcv[(H) * 8 + 2 * (K)], srcv[(H) * 8 + 2 * (K) + 1] };\
        f32x2 resv = sr - a0;           /* on A: src - f0 */                      \
        f32x2 gxv  = (a1 - a2) * 0.5f;  /* on A: (f1-f2)/2 */                     \
        SxxV += gxv * gxv; SxyV += gxv * gyv; SyyV += gyv * gyv;                  \
        TxV  += resv * gxv; TyV += resv * gyv; }
    PAIRSTEP(0, 0) PAIRSTEP(0, 1) PAIRSTEP(0, 2) PAIRSTEP(0, 3)
    PAIRSTEP(1, 0) PAIRSTEP(1, 1) PAIRSTEP(1, 2) PAIRSTEP(1, 3)
#undef PAIRSTEP
#undef MIX

    // B lanes carry garbage accumulators -> mask to zero
    const float Sxx = h ? 0.0f : (SxxV[0] + SxxV[1]);
    const float Sxy = h ? 0.0f : (SxyV[0] + SxyV[1]);
    const float Syy = h ? 0.0f : (SyyV[0] + SyyV[1]);
    const float Tx  = h ? 0.0f : (TxV[0]  + TxV[1]);
    const float Ty  = h ? 0.0f : (TyV[0]  + TyV[1]);

    // ---- Jacobian rows (after loop; X,Y,Z pair-uniform and valid on both lanes) ----
    const float fx = calibK[b * 9 + 0];
    const float fy = calibK[b * 9 + 4];
    const float fxZ = fx / Z, fyZ = fy / Z;
    const float fxXZ2 = fxZ * X / Z;
    const float fyYZ2 = fyZ * Y / Z;
    float r0[6] = { fxZ, 0.0f, -fxXZ2, -fxXZ2 * Y, fx + fxXZ2 * X, -fxZ * Y };
    float r1[6] = { 0.0f, fyZ, -fyYZ2, -fy - fyYZ2 * Y, fyYZ2 * X, fyZ * X };

    const float Pm = w * Sxx, Qm = w * Sxy, Rm = w * Syy;
    const float tx = w * Tx,  ty = w * Ty;

    // ---- rank-2 H: H(k,l) = r0[k]*a[l] + r1[k]*c[l]  (B lanes: all zero) ----
    float av[6], cv[6];
#pragma unroll
    for (int k = 0; k < 6; ++k) {
        av[k] = Pm * r0[k] + Qm * r1[k];
        cv[k] = Qm * r0[k] + Rm * r1[k];
    }

    // ---- 27 values: 4-step DPP row sum -> 16 LDS rows -> block combine ----
    const int wv   = t >> 6;
    const int lane = t & 63;
    const int rrow = (wv << 2) | (lane >> 4);
    const bool wr  = (lane & 15) == 15;

    int idx = 0;
#pragma unroll
    for (int k = 0; k < 6; ++k) {
#pragma unroll
        for (int l = 0; l < 6; ++l) {
            if (l < k) continue;
            float v = r0[k] * av[l] + r1[k] * cv[l];
            v = dpp_row_sum(v);
            if (wr) red[rrow][idx] = v;
            ++idx;
        }
    }
#pragma unroll
    for (int k = 0; k < 6; ++k) {
        float v = tx * r0[k] + ty * r1[k];
        v = dpp_row_sum(v);
        if (wr) red[rrow][21 + k] = v;
    }
    __syncthreads();
    if (t < NPART) {
        float s = 0.0f;
#pragma unroll
        for (int r = 0; r < 16; ++r) s += red[r][t];
        partials[((size_t)b * NBLK + blk) * NPART + t] = s;
    }
}

// ---------------- kernel 2: double reduce + solve + se3_exp + compose ----------------
__global__ __launch_bounds__(256) void gn_solve(
    const float* __restrict__ partials,
    const float* __restrict__ poses,
    float* __restrict__ out)
{
    const int b = blockIdx.x;
    const int t = threadIdx.x;
    __shared__ double dsum[8][NPART];
    __shared__ double sums[NPART];

    if (t < 216) {
        const int col = t % NPART;
        const int g   = t / NPART;
        double s = 0.0;
        for (int j = g; j < NBLK; j += 8)
            s += (double)partials[((size_t)b * NBLK + j) * NPART + col];
        dsum[g][col] = s;
    }
    __syncthreads();
    if (t < NPART) {
        double s = 0.0;
#pragma unroll
        for (int g = 0; g < 8; ++g) s += dsum[g][t];
        sums[t] = s;
    }
    __syncthreads();
    if (t != 0) return;

    double A[6][7];
    {
        int idx = 0;
        for (int k = 0; k < 6; ++k)
            for (int l = k; l < 6; ++l) {
                A[k][l] = sums[idx];
                A[l][k] = sums[idx];
                ++idx;
            }
        for (int k = 0; k < 6; ++k) A[k][6] = sums[21 + k];
    }
    for (int col = 0; col < 6; ++col) {
        int piv = col; double mx = fabs(A[col][col]);
        for (int rr = col + 1; rr < 6; ++rr) {
            double v = fabs(A[rr][col]);
            if (v > mx) { mx = v; piv = rr; }
        }
        if (piv != col)
            for (int j = col; j < 7; ++j) { double tmp = A[col][j]; A[col][j] = A[piv][j]; A[piv][j] = tmp; }
        double d = A[col][col];
        for (int rr = col + 1; rr < 6; ++rr) {
            double f = A[rr][col] / d;
            for (int j = col; j < 7; ++j) A[rr][j] -= f * A[col][j];
        }
    }
    double x[6];
    for (int i = 5; i >= 0; --i) {
        double s = A[i][6];
        for (int j = i + 1; j < 6; ++j) s -= A[i][j] * x[j];
        x[i] = s / A[i][i];
    }

    const double rho[3] = { x[0], x[1], x[2] };
    const double phi[3] = { x[3], x[4], x[5] };
    const double th2 = phi[0]*phi[0] + phi[1]*phi[1] + phi[2]*phi[2];
    const bool small = th2 < 1e-8;
    const double th2s = small ? 1.0 : th2;
    const double th = sqrt(th2s);
    const double Ac = small ? 1.0 - th2 / 6.0   : sin(th) / th;
    const double Bc = small ? 0.5 - th2 / 24.0  : (1.0 - cos(th)) / th2s;
    const double Cc = small ? 1.0/6.0 - th2/120.0 : (th - sin(th)) / (th2s * th);
    const double Kh[3][3] = { { 0.0, -phi[2],  phi[1] },
                              {  phi[2], 0.0, -phi[0] },
                              { -phi[1],  phi[0], 0.0 } };
    double K2[3][3];
    for (int i = 0; i < 3; ++i)
        for (int j = 0; j < 3; ++j) {
            double s = 0.0;
            for (int k = 0; k < 3; ++k) s += Kh[i][k] * Kh[k][j];
            K2[i][j] = s;
        }
    double T[4][4];
    for (int i = 0; i < 3; ++i)
        for (int j = 0; j < 3; ++j) {
            double I = (i == j) ? 1.0 : 0.0;
            T[i][j] = I + Ac * Kh[i][j] + Bc * K2[i][j];
        }
    for (int i = 0; i < 3; ++i) {
        double s = 0.0;
        for (int j = 0; j < 3; ++j) {
            double I = (i == j) ? 1.0 : 0.0;
            double V = I + Bc * Kh[i][j] + Cc * K2[i][j];
            s += V * rho[j];
        }
        T[i][3] = s;
    }
    T[3][0] = 0.0; T[3][1] = 0.0; T[3][2] = 0.0; T[3][3] = 1.0;

    const float* pz = poses + b * 16;
    for (int i = 0; i < 4; ++i)
        for (int j = 0; j < 4; ++j) {
            double s = 0.0;
            for (int k = 0; k < 4; ++k) s += T[i][k] * (double)pz[k * 4 + j];
            out[b * 16 + i * 4 + j] = (float)s;
        }
    for (int k = 0; k < 6; ++k)
        out[BATCH * 16 + b * 6 + k] = (float)x[k];
}

extern "C" void kernel_launch(void* const* d_in, const int* in_sizes, int n_in,
                              void* d_out, int out_size, void* d_ws, size_t ws_size,
                              hipStream_t stream) {
    const float* poses    = (const float*)d_in[0];
    const float* calibK   = (const float*)d_in[1];
    const float* p2       = (const float*)d_in[2];
    const float* P2       = (const float*)d_in[3];
    const float* weight   = (const float*)d_in[4];
    const float* src_feat = (const float*)d_in[5];
    const float* tgt_feat = (const float*)d_in[6];
    const float* src_w    = (const float*)d_in[7];
    const float* tgt_w    = (const float*)d_in[8];
    float* out = (float*)d_out;

    char*  rec      = (char*)d_ws;                               // 16*RECB = 7.9 MB
    char*  twr      = rec + (size_t)BATCH * RECB;                // 16*TWB  = 2.0 MB
    float* partials = (float*)(twr + (size_t)BATCH * TWB);       // 0.66 MB (total 10.5 MB)

    hipLaunchKernelGGL(build_maps, dim3(HW / 256, BATCH), dim3(256), 0, stream,
                       tgt_feat, tgt_w, rec, twr);
    hipLaunchKernelGGL(gn_accum, dim3(NBLK * BATCH), dim3(256), 0, stream,
                       p2, P2, calibK, weight, src_feat, src_w, twr, rec, partials);
    hipLaunchKernelGGL(gn_solve, dim3(BATCH), dim3(256), 0, stream,
                       partials, poses, out);
}

// Round 16
// 47.787 us; speedup vs baseline: 1.4743x; 1.2167x over previous
//
#include <hip/hip_runtime.h>
#include <math.h>

#define BATCH 16
#define CHN   16
#define IMH   96
#define IMW   320
#define HW    (IMH*IMW)          /* 30720 */
#define NBLK  (HW/256)           /* 120 blocks per batch */
#define NPART 27                 /* 21 (sym H) + 6 (b) */
#define TWB   (HW*4)             /* tgt_w corner-record bytes per batch */
#define RECB  (HW*16)            /* fp4 y-pair record map bytes per batch */

typedef __attribute__((ext_vector_type(2))) float f32x2;

// 4-step DPP row reduce (row_shr 1/2/4/8): lane 15+16r holds the sum of its 16-lane row.
__device__ __forceinline__ float dpp_row_sum(float x) {
    union fi { float f; int i; };
    fi v; v.f = x;
#define DPPSTEP(CTRL) { fi t; t.i = __builtin_amdgcn_update_dpp(0, v.i, CTRL, 0xf, 0xf, true); v.f += t.f; }
    DPPSTEP(0x111)
    DPPSTEP(0x112)
    DPPSTEP(0x114)
    DPPSTEP(0x118)
#undef DPPSTEP
    return v.f;
}

// ---- kernel 0: quantize tgt_feat to fp4 y-pair records; tgt_w 4-corner dwords ----
// Record (x,y), 16B: [pix(x,y) 8B fp4x16ch | pix(x,min(y+1,95)) 8B].
__global__ __launch_bounds__(256) void build_maps(const float* __restrict__ in,
                                                  const float* __restrict__ tw,
                                                  char* __restrict__ rec,
                                                  char* __restrict__ twr) {
    const int b = blockIdx.y;
    const int p = blockIdx.x * 256 + threadIdx.x;
    const int y = p / IMW, x = p - y * IMW;
    const float* ip = in + (size_t)b * CHN * HW + p;
    float f[16];
#pragma unroll
    for (int c = 0; c < 16; ++c) f[c] = ip[c * HW];

    unsigned d0 = 0, d1 = 0;
    d0 = __builtin_amdgcn_cvt_scalef32_pk_fp4_f32(d0, f[0],  f[1],  1.0f, 0);
    d0 = __builtin_amdgcn_cvt_scalef32_pk_fp4_f32(d0, f[2],  f[3],  1.0f, 1);
    d0 = __builtin_amdgcn_cvt_scalef32_pk_fp4_f32(d0, f[4],  f[5],  1.0f, 2);
    d0 = __builtin_amdgcn_cvt_scalef32_pk_fp4_f32(d0, f[6],  f[7],  1.0f, 3);
    d1 = __builtin_amdgcn_cvt_scalef32_pk_fp4_f32(d1, f[8],  f[9],  1.0f, 0);
    d1 = __builtin_amdgcn_cvt_scalef32_pk_fp4_f32(d1, f[10], f[11], 1.0f, 1);
    d1 = __builtin_amdgcn_cvt_scalef32_pk_fp4_f32(d1, f[12], f[13], 1.0f, 2);
    d1 = __builtin_amdgcn_cvt_scalef32_pk_fp4_f32(d1, f[14], f[15], 1.0f, 3);
    int2 lv; lv.x = (int)d0; lv.y = (int)d1;
    char* rb = rec + (size_t)b * RECB;
    *(int2*)(rb + (size_t)p * 16) = lv;                               // own record lo
    if (y > 0)        *(int2*)(rb + (size_t)(p - IMW) * 16 + 8) = lv; // record above, hi
    if (y == IMH - 1) *(int2*)(rb + (size_t)p * 16 + 8) = lv;         // clamp row

    const float* twb = tw + (size_t)b * HW;
    const int xp1 = min(x + 1, IMW - 1), yp1 = min(y + 1, IMH - 1);
    const float v00 = twb[p];
    const float v01 = twb[y * IMW + xp1];
    const float v10 = twb[yp1 * IMW + x];
    const float v11 = twb[yp1 * IMW + xp1];
    int wq = __builtin_amdgcn_cvt_pk_fp8_f32(v00, v01, 0, false);
    wq     = __builtin_amdgcn_cvt_pk_fp8_f32(v10, v11, wq, true);
    ((int*)(twr + (size_t)b * TWB))[p] = wq;
}

// ---- kernel 1: per-point moments + block-partial H/b ----
__global__ __launch_bounds__(256, 2) void gn_accum(
    const float* __restrict__ p2,
    const float* __restrict__ P2,
    const float* __restrict__ calibK,
    const float* __restrict__ weight,
    const float* __restrict__ src_feat,
    const float* __restrict__ src_w,
    const char* __restrict__ twr,
    const char* __restrict__ rec,
    float* __restrict__ partials)        // (B, NBLK, NPART)
{
    __shared__ float xs_l[1280];
    __shared__ float ys_l[1280];
    __shared__ float red[16][NPART];

    // XCD pinning: XCD k serves batches {k, k+8} -> 2 maps (~1 MB) per L2
    const int n   = blockIdx.x;
    const int b   = n & 15;
    const int blk = n >> 4;
    const int t   = threadIdx.x;
    const int p   = blk * 256 + t;

    // ---- cooperative coalesced stage of the block's 1280 grid coords ----
    const unsigned Gblk0 = ((unsigned)b * HW + (unsigned)(blk * 256)) * 5u;
#pragma unroll
    for (int j = 0; j < 5; ++j) {
        const unsigned idx  = (unsigned)(j * 256 + t);
        const unsigned G    = Gblk0 + idx;
        const unsigned sBig = G / (unsigned)(BATCH * HW);
        const unsigned r    = G - sBig * (unsigned)(BATCH * HW);
        const unsigned bb   = r / (unsigned)HW;
        const unsigned q    = r - bb * (unsigned)HW;
        const float* pb = p2 + (size_t)bb * (10 * HW) + (size_t)sBig * HW + q;
        xs_l[idx] = pb[0];
        ys_l[idx] = pb[5 * HW];
    }
    __syncthreads();

    // ---- per-point sample geometry from LDS ----
    float wxs[5], wys[5];
    int   off[5];
    int   twoff = 0;
#pragma unroll
    for (int s = 0; s < 5; ++s) {
        const float xp = xs_l[5 * t + s];
        const float yp = ys_l[5 * t + s];
        float gx = 2.0f * (xp + 0.5f) / (float)IMW - 1.0f;
        float gy = 2.0f * (yp + 0.5f) / (float)IMH - 1.0f;
        float x  = (gx + 1.0f) * ((float)IMW * 0.5f) - 0.5f;
        float y  = (gy + 1.0f) * ((float)IMH * 0.5f) - 0.5f;
        float x0 = floorf(x), y0 = floorf(y);
        wxs[s] = x - x0;
        wys[s] = y - y0;
        int xi = (int)x0, yi = (int)y0;
        xi = min(max(xi, 0), IMW - 2);
        yi = min(max(yi, 0), IMH - 2);
        off[s] = (yi * IMW + xi) * 16;
        if (s == 0) twoff = (yi * IMW + xi) * 4;
    }

    // ---- issue ALL scattered loads up front: 10 int4 gathers + twq ----
    const char* mapb = rec + (size_t)b * RECB;
    int4 L0[5], L1[5];
#pragma unroll
    for (int s = 0; s < 5; ++s) {
        L0[s] = *(const int4*)(mapb + off[s]);
        L1[s] = *(const int4*)(mapb + off[s] + 16);
    }
    const int twq = *(const int*)(twr + (size_t)b * TWB + twoff);

    float srcv[16];
    const float* srcb = src_feat + (size_t)b * CHN * HW + p;
#pragma unroll
    for (int c = 0; c < 16; ++c) srcv[c] = srcb[c * HW];

    const float* P2b = P2 + (size_t)b * 3 * HW;
    const float X = P2b[p], Y = P2b[HW + p], Z = P2b[2 * HW + p];
    const float wP  = weight[(size_t)b * HW + p];
    const float swP = src_w[(size_t)b * HW + p];

    // ---- latency fill: Jacobian rows + corner weights ----
    const float fx = calibK[b * 9 + 0];
    const float fy = calibK[b * 9 + 4];
    const float fxZ = fx / Z, fyZ = fy / Z;
    const float fxXZ2 = fxZ * X / Z;
    const float fyYZ2 = fyZ * Y / Z;
    float r0[6] = { fxZ, 0.0f, -fxXZ2, -fxXZ2 * Y, fx + fxXZ2 * X, -fxZ * Y };
    float r1[6] = { 0.0f, fyZ, -fyYZ2, -fy - fyYZ2 * Y, fyYZ2 * X, fyZ * X };

    float w00[5], w01[5], w10[5], w11[5];
#pragma unroll
    for (int s = 0; s < 5; ++s) {
        float wx = wxs[s], wy = wys[s];
        w00[s] = (1.0f - wx) * (1.0f - wy);
        w01[s] = wx * (1.0f - wy);
        w10[s] = (1.0f - wx) * wy;
        w11[s] = wx * wy;
    }

    float wtw;
    {
        const float wx = wxs[0], wy = wys[0];
        f32x2 wlo = __builtin_amdgcn_cvt_pk_f32_fp8(twq, false);
        f32x2 whi = __builtin_amdgcn_cvt_pk_f32_fp8(twq, true);
        wtw = wlo[0] * (1.0f - wx) * (1.0f - wy) + wlo[1] * wx * (1.0f - wy)
            + whi[0] * (1.0f - wx) * wy          + whi[1] * wx * wy;
    }
    const float w = swP * wtw * wP;

    // ---- decode fp4 + bilinear mix + moments ----
    // L0[s] = record(x0,y0)  = {p00.d0, p00.d1, p10.d0, p10.d1}
    // L1[s] = record(x0+1,y0)= {p01.d0, p01.d1, p11.d0, p11.d1}
    f32x2 SxxV = {0.f,0.f}, SxyV = {0.f,0.f}, SyyV = {0.f,0.f}, TxV = {0.f,0.f}, TyV = {0.f,0.f};
#define PAIRSTEP(H, K) {                                                          \
        f32x2 fsv[5];                                                             \
        _Pragma("unroll")                                                         \
        for (int s = 0; s < 5; ++s) {                                             \
            const int ad = (H) ? L0[s].y : L0[s].x;                               \
            const int bd = (H) ? L1[s].y : L1[s].x;                               \
            const int cd = (H) ? L0[s].w : L0[s].z;                               \
            const int dd = (H) ? L1[s].w : L1[s].z;                               \
            fsv[s] = __builtin_amdgcn_cvt_scalef32_pk_f32_fp4(ad, 1.0f, K) * w00[s] \
                   + __builtin_amdgcn_cvt_scalef32_pk_f32_fp4(bd, 1.0f, K) * w01[s] \
                   + __builtin_amdgcn_cvt_scalef32_pk_f32_fp4(cd, 1.0f, K) * w10[s] \
                   + __builtin_amdgcn_cvt_scalef32_pk_f32_fp4(dd, 1.0f, K) * w11[s]; \
        }                                                                         \
        const f32x2 sr = { srcv[(H) * 8 + 2 * (K)], srcv[(H) * 8 + 2 * (K) + 1] };\
        f32x2 resv = sr - fsv[0];                                                 \
        f32x2 gxv  = (fsv[1] - fsv[2]) * 0.5f;                                    \
        f32x2 gyv  = (fsv[3] - fsv[4]) * 0.5f;                                    \
        SxxV += gxv * gxv; SxyV += gxv * gyv; SyyV += gyv * gyv;                  \
        TxV  += resv * gxv; TyV += resv * gyv; }
    PAIRSTEP(0, 0) PAIRSTEP(0, 1) PAIRSTEP(0, 2) PAIRSTEP(0, 3)
    PAIRSTEP(1, 0) PAIRSTEP(1, 1) PAIRSTEP(1, 2) PAIRSTEP(1, 3)
#undef PAIRSTEP

    const float Sxx = SxxV[0] + SxxV[1];
    const float Sxy = SxyV[0] + SxyV[1];
    const float Syy = SyyV[0] + SyyV[1];
    const float Tx  = TxV[0]  + TxV[1];
    const float Ty  = TyV[0]  + TyV[1];

    const float Pm = w * Sxx, Qm = w * Sxy, Rm = w * Syy;
    const float tx = w * Tx,  ty = w * Ty;

    // ---- rank-2 H: H(k,l) = r0[k]*a[l] + r1[k]*c[l] ----
    float av[6], cv[6];
#pragma unroll
    for (int k = 0; k < 6; ++k) {
        av[k] = Pm * r0[k] + Qm * r1[k];
        cv[k] = Qm * r0[k] + Rm * r1[k];
    }

    // ---- 27 values: 4-step DPP row sum -> 16 LDS rows -> block combine ----
    const int wv   = t >> 6;
    const int lane = t & 63;
    const int rrow = (wv << 2) | (lane >> 4);
    const bool wr  = (lane & 15) == 15;

    int idx = 0;
#pragma unroll
    for (int k = 0; k < 6; ++k) {
#pragma unroll
        for (int l = 0; l < 6; ++l) {
            if (l < k) continue;
            float v = r0[k] * av[l] + r1[k] * cv[l];
            v = dpp_row_sum(v);
            if (wr) red[rrow][idx] = v;
            ++idx;
        }
    }
#pragma unroll
    for (int k = 0; k < 6; ++k) {
        float v = tx * r0[k] + ty * r1[k];
        v = dpp_row_sum(v);
        if (wr) red[rrow][21 + k] = v;
    }
    __syncthreads();
    if (t < NPART) {
        float s = 0.0f;
#pragma unroll
        for (int r = 0; r < 16; ++r) s += red[r][t];
        partials[((size_t)b * NBLK + blk) * NPART + t] = s;
    }
}

// ---------------- kernel 2: double reduce + solve + se3_exp + compose ----------------
__global__ __launch_bounds__(256) void gn_solve(
    const float* __restrict__ partials,
    const float* __restrict__ poses,
    float* __restrict__ out)
{
    const int b = blockIdx.x;
    const int t = threadIdx.x;
    __shared__ double dsum[8][NPART];
    __shared__ double sums[NPART];

    if (t < 216) {
        const int col = t % NPART;
        const int g   = t / NPART;
        double s = 0.0;
        for (int j = g; j < NBLK; j += 8)
            s += (double)partials[((size_t)b * NBLK + j) * NPART + col];
        dsum[g][col] = s;
    }
    __syncthreads();
    if (t < NPART) {
        double s = 0.0;
#pragma unroll
        for (int g = 0; g < 8; ++g) s += dsum[g][t];
        sums[t] = s;
    }
    __syncthreads();
    if (t != 0) return;

    double A[6][7];
    {
        int idx = 0;
        for (int k = 0; k < 6; ++k)
            for (int l = k; l < 6; ++l) {
                A[k][l] = sums[idx];
                A[l][k] = sums[idx];
                ++idx;
            }
        for (int k = 0; k < 6; ++k) A[k][6] = sums[21 + k];
    }
    for (int col = 0; col < 6; ++col) {
        int piv = col; double mx = fabs(A[col][col]);
        for (int rr = col + 1; rr < 6; ++rr) {
            double v = fabs(A[rr][col]);
            if (v > mx) { mx = v; piv = rr; }
        }
        if (piv != col)
            for (int j = col; j < 7; ++j) { double tmp = A[col][j]; A[col][j] = A[piv][j]; A[piv][j] = tmp; }
        double d = A[col][col];
        for (int rr = col + 1; rr < 6; ++rr) {
            double f = A[rr][col] / d;
            for (int j = col; j < 7; ++j) A[rr][j] -= f * A[col][j];
        }
    }
    double x[6];
    for (int i = 5; i >= 0; --i) {
        double s = A[i][6];
        for (int j = i + 1; j < 6; ++j) s -= A[i][j] * x[j];
        x[i] = s / A[i][i];
    }

    const double rho[3] = { x[0], x[1], x[2] };
    const double phi[3] = { x[3], x[4], x[5] };
    const double th2 = phi[0]*phi[0] + phi[1]*phi[1] + phi[2]*phi[2];
    const bool small = th2 < 1e-8;
    const double th2s = small ? 1.0 : th2;
    const double th = sqrt(th2s);
    const double Ac = small ? 1.0 - th2 / 6.0   : sin(th) / th;
    const double Bc = small ? 0.5 - th2 / 24.0  : (1.0 - cos(th)) / th2s;
    const double Cc = small ? 1.0/6.0 - th2/120.0 : (th - sin(th)) / (th2s * th);
    const double Kh[3][3] = { { 0.0, -phi[2],  phi[1] },
                              {  phi[2], 0.0, -phi[0] },
                              { -phi[1],  phi[0], 0.0 } };
    double K2[3][3];
    for (int i = 0; i < 3; ++i)
        for (int j = 0; j < 3; ++j) {
            double s = 0.0;
            for (int k = 0; k < 3; ++k) s += Kh[i][k] * Kh[k][j];
            K2[i][j] = s;
        }
    double T[4][4];
    for (int i = 0; i < 3; ++i)
        for (int j = 0; j < 3; ++j) {
            double I = (i == j) ? 1.0 : 0.0;
            T[i][j] = I + Ac * Kh[i][j] + Bc * K2[i][j];
        }
    for (int i = 0; i < 3; ++i) {
        double s = 0.0;
        for (int j = 0; j < 3; ++j) {
            double I = (i == j) ? 1.0 : 0.0;
            double V = I + Bc * Kh[i][j] + Cc * K2[i][j];
            s += V * rho[j];
        }
        T[i][3] = s;
    }
    T[3][0] = 0.0; T[3][1] = 0.0; T[3][2] = 0.0; T[3][3] = 1.0;

    const float* pz = poses + b * 16;
    for (int i = 0; i < 4; ++i)
        for (int j = 0; j < 4; ++j) {
            double s = 0.0;
            for (int k = 0; k < 4; ++k) s += T[i][k] * (double)pz[k * 4 + j];
            out[b * 16 + i * 4 + j] = (float)s;
        }
    for (int k = 0; k < 6; ++k)
        out[BATCH * 16 + b * 6 + k] = (float)x[k];
}

extern "C" void kernel_launch(void* const* d_in, const int* in_sizes, int n_in,
                              void* d_out, int out_size, void* d_ws, size_t ws_size,
                              hipStream_t stream) {
    const float* poses    = (const float*)d_in[0];
    const float* calibK   = (const float*)d_in[1];
    const float* p2       = (const float*)d_in[2];
    const float* P2       = (const float*)d_in[3];
    const float* weight   = (const float*)d_in[4];
    const float* src_feat = (const float*)d_in[5];
    const float* tgt_feat = (const float*)d_in[6];
    const float* src_w    = (const float*)d_in[7];
    const float* tgt_w    = (const float*)d_in[8];
    float* out = (float*)d_out;

    char*  rec      = (char*)d_ws;                               // 16*RECB = 7.9 MB
    char*  twr      = rec + (size_t)BATCH * RECB;                // 16*TWB  = 2.0 MB
    float* partials = (float*)(twr + (size_t)BATCH * TWB);       // 0.2 MB  (total 10.1 MB)

    hipLaunchKernelGGL(build_maps, dim3(HW / 256, BATCH), dim3(256), 0, stream,
                       tgt_feat, tgt_w, rec, twr);
    hipLaunchKernelGGL(gn_accum, dim3(NBLK * BATCH), dim3(256), 0, stream,
                       p2, P2, calibK, weight, src_feat, src_w, twr, rec, partials);
    hipLaunchKernelGGL(gn_solve, dim3(BATCH), dim3(256), 0, stream,
                       partials, poses, out);
}